// Round 4
// baseline (382.321 us; speedup 1.0000x reference)
//
#include <hip/hip_runtime.h>
#include <stdint.h>

typedef __bf16 bf16;
typedef __attribute__((ext_vector_type(4))) __bf16 bf16x4;
typedef __attribute__((ext_vector_type(8))) __bf16 bf16x8;
typedef __attribute__((ext_vector_type(4))) float f32x4;

constexpr int S = 2048;
constexpr int D = 1024;
constexpr int H = 16;
constexpr int DH = 64;
constexpr int M = 4096;  // B*S

constexpr float QSCALE = 0.18033688011112042f;  // 0.125 * log2(e)

// async global->LDS, 16B per lane; LDS dst = (wave-uniform base) + lane*16
__device__ __forceinline__ void async16(void* lds, const void* g) {
  __builtin_amdgcn_global_load_lds(
      (const __attribute__((address_space(1))) void*)g,
      (__attribute__((address_space(3))) void*)lds, 16, 0, 0);
}

// ===================== weight transpose prepass =====================
// W [k][n] fp32 -> WT [n][k] bf16 (z<3: hi only; z==3: W_o -> hi and lo)
__global__ __launch_bounds__(256) void wtrans(
    const float* __restrict__ Wq, const float* __restrict__ Wk,
    const float* __restrict__ Wv, const float* __restrict__ Wo,
    bf16* __restrict__ WTq, bf16* __restrict__ WTk, bf16* __restrict__ WTv,
    bf16* __restrict__ WoTh, bf16* __restrict__ WoTl) {
  __shared__ float T[64 * 68];
  const int z = blockIdx.z;
  const float* W = (z == 0) ? Wq : (z == 1) ? Wk : (z == 2) ? Wv : Wo;
  const int n0 = blockIdx.x * 64, k0 = blockIdx.y * 64;
  const int tid = threadIdx.x;
  const int lr = tid >> 4, lc = (tid & 15) * 4;
#pragma unroll
  for (int r = 0; r < 4; r++) {
    f32x4 v = *(const f32x4*)(W + (size_t)(k0 + r * 16 + lr) * 1024 + n0 + lc);
    *(f32x4*)&T[(r * 16 + lr) * 68 + lc] = v;
  }
  __syncthreads();
  const int nn = tid >> 3, kc = (tid & 7) * 8;
#pragma unroll
  for (int p = 0; p < 2; p++) {
    int n = p * 32 + nn;
    bf16x8 h, l;
#pragma unroll
    for (int j = 0; j < 8; j++) {
      float v = T[(kc + j) * 68 + n];
      bf16 hh = (bf16)v;
      h[j] = hh;
      l[j] = (bf16)(v - (float)hh);
    }
    if (z < 3) {
      bf16* WT = (z == 0) ? WTq : (z == 1) ? WTk : WTv;
      *(bf16x8*)(WT + (size_t)(n0 + n) * 1024 + k0 + kc) = h;
    } else {
      *(bf16x8*)(WoTh + (size_t)(n0 + n) * 1024 + k0 + kc) = h;
      *(bf16x8*)(WoTl + (size_t)(n0 + n) * 1024 + k0 + kc) = l;
    }
  }
}

// ===================== fused QKV GEMM (plain bf16, m97 structure) =====================
// A fp32 [M][1024] staged raw to LDS via global_load_lds (cvt at frag read);
// WT bf16 [n][k] staged via global_load_lds. 128x128 tile, BK=32.
// z=0: Q*QSCALE -> bf16 [B,H,S,DH]; z=1: K; z=2: V^T [B*H,DH,S].
__global__ __launch_bounds__(256) void gemm_qkv(
    const float* __restrict__ Aq, const float* __restrict__ Ak,
    const float* __restrict__ Av, const bf16* __restrict__ WTq,
    const bf16* __restrict__ WTk, const bf16* __restrict__ WTv,
    const float* __restrict__ bq, const float* __restrict__ bk,
    const float* __restrict__ bv, bf16* __restrict__ Qb,
    bf16* __restrict__ Kb, bf16* __restrict__ VT) {
  __shared__ char smem[34816];       // staging 24576 B; epilogue T 34816 B
  float* As = (float*)smem;          // [128][32] fp32, granule-swizzled
  bf16* Bs = (bf16*)(smem + 16384);  // [128][32] bf16, granule-rotated

  const int z = blockIdx.z;
  const float* A = (z == 0) ? Aq : (z == 1) ? Ak : Av;
  const bf16* WT = (z == 0) ? WTq : (z == 1) ? WTk : WTv;
  const float* bias = (z == 0) ? bq : (z == 1) ? bk : bv;
  const float oscale = (z == 0) ? QSCALE : 1.0f;

  const int tid = threadIdx.x;
  const int bn = blockIdx.x * 128;
  const int bm = blockIdx.y * 128;
  const int wv = tid >> 6;
  const int lane = tid & 63;
  const int quad = lane >> 4;
  const int lo = lane & 15;
  const int wm = (wv >> 1) * 64;
  const int wn = (wv & 1) * 64;

  f32x4 acc[4][4];
#pragma unroll
  for (int i = 0; i < 4; i++)
#pragma unroll
    for (int j = 0; j < 4; j++) acc[i][j] = {0.f, 0.f, 0.f, 0.f};

  // staging lane decomposition
  const int r8 = lane >> 3;                 // A: row within 8-row group
  const int agp = (lane & 7) ^ r8;          // A: swizzled global granule (16B)
  const int n4 = lane >> 2;                 // B: row within 16-row group
  const int brot = (n4 + (n4 >> 2)) & 3;
  const int bgq = ((lane & 3) - brot) & 3;  // B: rotated global granule
  const int rotr = (lo + (lo >> 2)) & 3;    // B frag-read rotation

  for (int kt = 0; kt < 32; ++kt) {
#pragma unroll
    for (int j = 0; j < 4; j++) {  // A tile: 16 instrs (4/wave)
      int row0 = wv * 32 + j * 8;
      async16(smem + row0 * 128,
              A + (size_t)(bm + row0 + r8) * 1024 + kt * 32 + agp * 4);
    }
#pragma unroll
    for (int j = 0; j < 2; j++) {  // B tile: 8 instrs (2/wave)
      int nrow0 = wv * 32 + j * 16;
      async16(smem + 16384 + nrow0 * 64,
              WT + (size_t)(bn + nrow0 + n4) * 1024 + kt * 32 + bgq * 8);
    }
    __syncthreads();

    bf16x8 af[4], bf[4];
#pragma unroll
    for (int mi = 0; mi < 4; mi++) {
      int row = wm + mi * 16 + lo;
      int sw = row & 7;
      f32x4 x0 = *(const f32x4*)(smem + row * 128 + (((quad * 2) ^ sw) * 16));
      f32x4 x1 = *(const f32x4*)(smem + row * 128 + (((quad * 2 + 1) ^ sw) * 16));
      bf16x8 a;
#pragma unroll
      for (int j = 0; j < 4; j++) {
        a[j] = (bf16)x0[j];
        a[4 + j] = (bf16)x1[j];
      }
      af[mi] = a;
    }
#pragma unroll
    for (int ni = 0; ni < 4; ni++) {
      int nrow = wn + ni * 16 + lo;
      bf[ni] = *(const bf16x8*)(smem + 16384 + nrow * 64 + (((quad + rotr) & 3) * 16));
    }
#pragma unroll
    for (int mi = 0; mi < 4; mi++)
#pragma unroll
      for (int ni = 0; ni < 4; ni++)
        acc[mi][ni] = __builtin_amdgcn_mfma_f32_16x16x32_bf16(af[mi], bf[ni], acc[mi][ni], 0, 0, 0);
    __syncthreads();
  }

  const int b = bm >> 11;
  const int srow0 = bm & (S - 1);

  if (z == 2) {  // V^T: direct bf16x4 stores [bh][dh][s]
#pragma unroll
    for (int mi = 0; mi < 4; mi++)
#pragma unroll
      for (int ni = 0; ni < 4; ni++) {
        int col = bn + wn + ni * 16 + lo;
        int h = col >> 6, dh = col & 63;
        float bvv = bias[col];
        bf16x4 t;
#pragma unroll
        for (int r = 0; r < 4; r++) t[r] = (bf16)(acc[mi][ni][r] + bvv);
        int s0 = srow0 + wm + mi * 16 + quad * 4;
        *(bf16x4*)&VT[(((size_t)(b * H + h)) * DH + dh) * S + s0] = t;
      }
    return;
  }

  // Q/K: LDS transpose -> coalesced [bh][s][dh] stores
  bf16* T = (bf16*)smem;  // [128][136]
#pragma unroll
  for (int mi = 0; mi < 4; mi++)
#pragma unroll
    for (int ni = 0; ni < 4; ni++) {
      int col = wn + ni * 16 + lo;
      float bvv = bias[bn + col];
#pragma unroll
      for (int r = 0; r < 4; r++) {
        int row = wm + mi * 16 + quad * 4 + r;
        T[row * 136 + col] = (bf16)((acc[mi][ni][r] + bvv) * oscale);
      }
    }
  __syncthreads();
  bf16* out = (z == 0) ? Qb : Kb;
  const int rr = tid >> 1;
  const int half = tid & 1;
  const int h = (bn >> 6) + half;
  bf16* gp = out + (((size_t)(b * H + h)) * S + srow0 + rr) * DH;
#pragma unroll
  for (int j = 0; j < 8; j++)
    *(bf16x8*)(gp + j * 8) = *(const bf16x8*)&T[rr * 136 + half * 64 + j * 8];
}

// ===================== O-projection GEMM (3-term split via z) =====================
// z=0: hi(AO)*WoTh -> P0 ; z=1: hi(AO)*WoTl -> P1 ; z=2: lo(AO)*WoTh -> d_out
__global__ __launch_bounds__(256) void gemm_o(
    const float* __restrict__ AO, const bf16* __restrict__ WoTh,
    const bf16* __restrict__ WoTl, float* __restrict__ P0,
    float* __restrict__ P1, float* __restrict__ dout) {
  __shared__ char smem[24576];
  bf16* dummy = nullptr;
  (void)dummy;

  const int z = blockIdx.z;
  const bf16* WT = (z == 1) ? WoTl : WoTh;
  float* out = (z == 0) ? P0 : (z == 1) ? P1 : dout;

  const int tid = threadIdx.x;
  const int bn = blockIdx.x * 128;
  const int bm = blockIdx.y * 128;
  const int wv = tid >> 6;
  const int lane = tid & 63;
  const int quad = lane >> 4;
  const int lo = lane & 15;
  const int wm = (wv >> 1) * 64;
  const int wn = (wv & 1) * 64;

  f32x4 acc[4][4];
#pragma unroll
  for (int i = 0; i < 4; i++)
#pragma unroll
    for (int j = 0; j < 4; j++) acc[i][j] = {0.f, 0.f, 0.f, 0.f};

  const int r8 = lane >> 3;
  const int agp = (lane & 7) ^ r8;
  const int n4 = lane >> 2;
  const int brot = (n4 + (n4 >> 2)) & 3;
  const int bgq = ((lane & 3) - brot) & 3;
  const int rotr = (lo + (lo >> 2)) & 3;

  for (int kt = 0; kt < 32; ++kt) {
#pragma unroll
    for (int j = 0; j < 4; j++) {
      int row0 = wv * 32 + j * 8;
      async16(smem + row0 * 128,
              AO + (size_t)(bm + row0 + r8) * 1024 + kt * 32 + agp * 4);
    }
#pragma unroll
    for (int j = 0; j < 2; j++) {
      int nrow0 = wv * 32 + j * 16;
      async16(smem + 16384 + nrow0 * 64,
              WT + (size_t)(bn + nrow0 + n4) * 1024 + kt * 32 + bgq * 8);
    }
    __syncthreads();

    bf16x8 af[4], bf[4];
#pragma unroll
    for (int mi = 0; mi < 4; mi++) {
      int row = wm + mi * 16 + lo;
      int sw = row & 7;
      f32x4 x0 = *(const f32x4*)(smem + row * 128 + (((quad * 2) ^ sw) * 16));
      f32x4 x1 = *(const f32x4*)(smem + row * 128 + (((quad * 2 + 1) ^ sw) * 16));
      bf16x8 a;
      if (z == 2) {
#pragma unroll
        for (int j = 0; j < 4; j++) {
          bf16 h0 = (bf16)x0[j];
          a[j] = (bf16)(x0[j] - (float)h0);
          bf16 h1 = (bf16)x1[j];
          a[4 + j] = (bf16)(x1[j] - (float)h1);
        }
      } else {
#pragma unroll
        for (int j = 0; j < 4; j++) {
          a[j] = (bf16)x0[j];
          a[4 + j] = (bf16)x1[j];
        }
      }
      af[mi] = a;
    }
#pragma unroll
    for (int ni = 0; ni < 4; ni++) {
      int nrow = wn + ni * 16 + lo;
      bf[ni] = *(const bf16x8*)(smem + 16384 + nrow * 64 + (((quad + rotr) & 3) * 16));
    }
#pragma unroll
    for (int mi = 0; mi < 4; mi++)
#pragma unroll
      for (int ni = 0; ni < 4; ni++)
        acc[mi][ni] = __builtin_amdgcn_mfma_f32_16x16x32_bf16(af[mi], bf[ni], acc[mi][ni], 0, 0, 0);
    __syncthreads();
  }

#pragma unroll
  for (int mi = 0; mi < 4; mi++)
#pragma unroll
    for (int ni = 0; ni < 4; ni++) {
      int col = bn + wn + ni * 16 + lo;
#pragma unroll
      for (int r = 0; r < 4; r++) {
        int row = bm + wm + mi * 16 + quad * 4 + r;
        out[(size_t)row * 1024 + col] = acc[mi][ni][r];
      }
    }
}

// ===================== reduce: d_out += P0 + P1 + bias =====================
__global__ __launch_bounds__(256) void reduce_o(const float* __restrict__ P0,
                                                const float* __restrict__ P1,
                                                const float* __restrict__ bias,
                                                float* __restrict__ out) {
  const size_t i = ((size_t)blockIdx.x * 256 + threadIdx.x) * 4;
  f32x4 a = *(const f32x4*)(out + i);
  f32x4 p0 = *(const f32x4*)(P0 + i);
  f32x4 p1 = *(const f32x4*)(P1 + i);
  f32x4 bv = *(const f32x4*)(bias + ((int)i & 1023));
  f32x4 r;
#pragma unroll
  for (int j = 0; j < 4; j++) r[j] = a[j] + p0[j] + p1[j] + bv[j];
  *(f32x4*)(out + i) = r;
}

// ===================== mask -> bitmask =====================
__global__ __launch_bounds__(256) void maskbits_kernel(
    const int* __restrict__ mask, uint64_t* __restrict__ MB) {
  const int gid = blockIdx.x * 4 + (threadIdx.x >> 6);
  const int lane = threadIdx.x & 63;
  const int kt = gid >> 11;
  const int q = gid & (S - 1);
  int v = mask[(size_t)q * S + kt * 64 + lane];
  uint64_t bits = __ballot(v != 0);
  if (lane == 0) MB[(size_t)kt * S + q] = bits;
}

// ===================== attention: 1024 blocks, 4-way key-split =====================
constexpr int LDP = 72;

__global__ __launch_bounds__(512, 4) void attn_kernel(
    const bf16* __restrict__ Qg, const bf16* __restrict__ Kg,
    const bf16* __restrict__ VTg, const uint64_t* __restrict__ MB,
    float* __restrict__ Og) {
  __shared__ bf16 Ps[8][32 * LDP];  // 36864 B; also the combine buffer

  const int tid = threadIdx.x;
  const int wv = tid >> 6;
  const int lane = tid & 63;
  const int quad = lane >> 4;
  const int lo = lane & 15;
  const int wq = wv >> 2;  // q-group (2 x 32 rows)
  const int ks = wv & 3;   // key-split quarter

  const int lin = blockIdx.x;  // 1024 blocks
  const int bh = (lin & 7) * 4 + ((lin >> 3) & 3);  // XCD-local K/V set
  const int qt = lin >> 5;                          // 0..31
  const int qbase = qt * 64 + wq * 32;
  const size_t base = (size_t)bh * S * DH;
  bf16* Pw = Ps[wv];

  bf16x8 qf[2][2];
#pragma unroll
  for (int nq = 0; nq < 2; nq++) {
    const bf16* qp = Qg + base + (size_t)(qbase + nq * 16 + lo) * DH + quad * 8;
    qf[nq][0] = *(const bf16x8*)qp;
    qf[nq][1] = *(const bf16x8*)(qp + 32);
  }

  f32x4 Oacc[2][4];
#pragma unroll
  for (int i = 0; i < 2; i++)
#pragma unroll
    for (int j = 0; j < 4; j++) Oacc[i][j] = {0.f, 0.f, 0.f, 0.f};
  float lpart[2] = {0.f, 0.f};

  for (int kt = ks * 8; kt < ks * 8 + 8; ++kt) {
    uint64_t m0 = MB[(size_t)kt * S + qbase + lo] >> (quad * 4);
    uint64_t m1 = MB[(size_t)kt * S + qbase + 16 + lo] >> (quad * 4);
    uint32_t mw[2][2] = {{(uint32_t)m0, (uint32_t)(m0 >> 32)},
                         {(uint32_t)m1, (uint32_t)(m1 >> 32)}};

    f32x4 sacc[4][2];
#pragma unroll
    for (int mi = 0; mi < 4; mi++)
#pragma unroll
      for (int nq = 0; nq < 2; nq++) sacc[mi][nq] = {0.f, 0.f, 0.f, 0.f};
#pragma unroll
    for (int mi = 0; mi < 4; mi++) {
      const bf16* kp = Kg + base + (size_t)(kt * 64 + mi * 16 + lo) * DH + quad * 8;
      bf16x8 k0 = *(const bf16x8*)kp;
      bf16x8 k1 = *(const bf16x8*)(kp + 32);
#pragma unroll
      for (int nq = 0; nq < 2; nq++) {
        sacc[mi][nq] = __builtin_amdgcn_mfma_f32_16x16x32_bf16(k0, qf[nq][0], sacc[mi][nq], 0, 0, 0);
        sacc[mi][nq] = __builtin_amdgcn_mfma_f32_16x16x32_bf16(k1, qf[nq][1], sacc[mi][nq], 0, 0, 0);
      }
    }

#pragma unroll
    for (int mi = 0; mi < 4; mi++)
#pragma unroll
      for (int nq = 0; nq < 2; nq++) {
        bf16x4 t;
#pragma unroll
        for (int r = 0; r < 4; r++) {
          float p = exp2f(sacc[mi][nq][r]);
          p = ((mw[nq][mi >> 1] >> (((mi & 1) << 4) + r)) & 1) ? p : 0.0f;
          lpart[nq] += p;
          t[r] = (bf16)p;
        }
        *(bf16x4*)&Pw[(nq * 16 + lo) * LDP + mi * 16 + quad * 4] = t;
      }

#pragma unroll
    for (int kk = 0; kk < 2; kk++) {
      bf16x8 pa0 = *(const bf16x8*)&Pw[lo * LDP + kk * 32 + quad * 8];
      bf16x8 pa1 = *(const bf16x8*)&Pw[(16 + lo) * LDP + kk * 32 + quad * 8];
#pragma unroll
      for (int ni = 0; ni < 4; ni++) {
        bf16x8 vb = *(const bf16x8*)(VTg + ((size_t)bh * DH + ni * 16 + lo) * S +
                                     kt * 64 + kk * 32 + quad * 8);
        Oacc[0][ni] = __builtin_amdgcn_mfma_f32_16x16x32_bf16(pa0, vb, Oacc[0][ni], 0, 0, 0);
        Oacc[1][ni] = __builtin_amdgcn_mfma_f32_16x16x32_bf16(pa1, vb, Oacc[1][ni], 0, 0, 0);
      }
    }
  }

#pragma unroll
  for (int nq = 0; nq < 2; nq++) {
    lpart[nq] += __shfl_xor(lpart[nq], 16);
    lpart[nq] += __shfl_xor(lpart[nq], 32);
  }

  // ---- 4-way combine through LDS (2 rounds) ----
  float* CB = (float*)Ps;
  const int lslot = lane * 36;
  __syncthreads();
  if (ks >= 2) {
    float* p = CB + (size_t)(wq * 2 + (ks - 2)) * 2304 + lslot;
#pragma unroll
    for (int qmi = 0; qmi < 2; qmi++)
#pragma unroll
      for (int ni = 0; ni < 4; ni++) *(f32x4*)(p + (qmi * 4 + ni) * 4) = Oacc[qmi][ni];
    p[32] = lpart[0];
    p[33] = lpart[1];
  }
  __syncthreads();
  if (ks < 2) {
    float* p = CB + (size_t)(wq * 2 + ks) * 2304 + lslot;
#pragma unroll
    for (int qmi = 0; qmi < 2; qmi++)
#pragma unroll
      for (int ni = 0; ni < 4; ni++) {
        f32x4 o = *(const f32x4*)(p + (qmi * 4 + ni) * 4);
#pragma unroll
        for (int r = 0; r < 4; r++) Oacc[qmi][ni][r] += o[r];
      }
    lpart[0] += p[32];
    lpart[1] += p[33];
  }
  __syncthreads();
  if (ks == 1) {
    float* p = CB + (size_t)wq * 2304 + lslot;
#pragma unroll
    for (int qmi = 0; qmi < 2; qmi++)
#pragma unroll
      for (int ni = 0; ni < 4; ni++) *(f32x4*)(p + (qmi * 4 + ni) * 4) = Oacc[qmi][ni];
    p[32] = lpart[0];
    p[33] = lpart[1];
  }
  __syncthreads();
  if (ks == 0) {
    float* p = CB + (size_t)wq * 2304 + lslot;
#pragma unroll
    for (int qmi = 0; qmi < 2; qmi++)
#pragma unroll
      for (int ni = 0; ni < 4; ni++) {
        f32x4 o = *(const f32x4*)(p + (qmi * 4 + ni) * 4);
#pragma unroll
        for (int r = 0; r < 4; r++) Oacc[qmi][ni][r] += o[r];
      }
    lpart[0] += p[32];
    lpart[1] += p[33];

    const int b = bh >> 4, h = bh & (H - 1);
#pragma unroll
    for (int qmi = 0; qmi < 2; qmi++)
#pragma unroll
      for (int r = 0; r < 4; r++) {
        float inv = 1.0f / __shfl(lpart[qmi], quad * 4 + r);
        int q = qbase + qmi * 16 + quad * 4 + r;
#pragma unroll
        for (int ni = 0; ni < 4; ni++)
          Og[(size_t)(b * S + q) * D + h * DH + ni * 16 + lo] = Oacc[qmi][ni][r] * inv;
      }
  }
}

// ===================== launch =====================
extern "C" void kernel_launch(void* const* d_in, const int* in_sizes, int n_in,
                              void* d_out, int out_size, void* d_ws,
                              size_t ws_size, hipStream_t stream) {
  const float* q = (const float*)d_in[0];
  const float* k = (const float*)d_in[1];
  const float* v = (const float*)d_in[2];
  const int* mask = (const int*)d_in[3];
  const float* w_q = (const float*)d_in[4];
  const float* b_q = (const float*)d_in[5];
  const float* w_k = (const float*)d_in[6];
  const float* b_k = (const float*)d_in[7];
  const float* w_v = (const float*)d_in[8];
  const float* b_v = (const float*)d_in[9];
  const float* w_o = (const float*)d_in[10];
  const float* b_o = (const float*)d_in[11];

  // ws layout (1 MiB units):
  // [0,16) AO fp32 | [16,24) Qb | [24,32) Kb | [32,40) VT | [40,48) scratch
  // P0 = [16,32) (overlays Qb+Kb, dead after attn) ; P1 = [32,48)
  // [48,50) WTq | [50,52) WTk | [52,54) WTv | [54,56) WoTh | [56,58) WoTl | [58,58.5) MB
  char* w = (char*)d_ws;
  const size_t MiB = 1ull << 20;
  float* AO = (float*)w;
  bf16* Qb = (bf16*)(w + 16 * MiB);
  bf16* Kb = (bf16*)(w + 24 * MiB);
  bf16* VT = (bf16*)(w + 32 * MiB);
  float* P0 = (float*)(w + 16 * MiB);
  float* P1 = (float*)(w + 32 * MiB);
  bf16* WTq = (bf16*)(w + 48 * MiB);
  bf16* WTk = (bf16*)(w + 50 * MiB);
  bf16* WTv = (bf16*)(w + 52 * MiB);
  bf16* WoTh = (bf16*)(w + 54 * MiB);
  bf16* WoTl = (bf16*)(w + 56 * MiB);
  uint64_t* MBits = (uint64_t*)(w + 58 * MiB);

  maskbits_kernel<<<16384, 256, 0, stream>>>(mask, MBits);
  wtrans<<<dim3(16, 16, 4), 256, 0, stream>>>(w_q, w_k, w_v, w_o, WTq, WTk, WTv,
                                              WoTh, WoTl);
  gemm_qkv<<<dim3(8, 32, 3), 256, 0, stream>>>(q, k, v, WTq, WTk, WTv, b_q, b_k,
                                               b_v, Qb, Kb, VT);
  attn_kernel<<<dim3(1024), 512, 0, stream>>>(Qb, Kb, VT, MBits, AO);
  gemm_o<<<dim3(8, 32, 3), 256, 0, stream>>>(AO, WoTh, WoTl, P0, P1,
                                             (float*)d_out);
  reduce_o<<<4096, 256, 0, stream>>>(P0, P1, b_o, (float*)d_out);
}

// Round 5
// 360.147 us; speedup vs baseline: 1.0616x; 1.0616x over previous
//
#include <hip/hip_runtime.h>
#include <stdint.h>

typedef __bf16 bf16;
typedef __attribute__((ext_vector_type(4))) __bf16 bf16x4;
typedef __attribute__((ext_vector_type(8))) __bf16 bf16x8;
typedef __attribute__((ext_vector_type(4))) float f32x4;

constexpr int S = 2048;
constexpr int D = 1024;
constexpr int H = 16;
constexpr int DH = 64;
constexpr int M = 4096;  // B*S

constexpr float QSCALE = 0.18033688011112042f;  // 0.125 * log2(e)

// async global->LDS, 16B/lane; LDS dst = wave-uniform base + lane*16
__device__ __forceinline__ void async16(void* lds, const void* g) {
  __builtin_amdgcn_global_load_lds(
      (const __attribute__((address_space(1))) void*)g,
      (__attribute__((address_space(3))) void*)lds, 16, 0, 0);
}

// ===================== cvt3: q,k,v fp32 -> bf16 =====================
__global__ __launch_bounds__(256) void cvt3(const float* __restrict__ q,
                                            const float* __restrict__ k,
                                            const float* __restrict__ v,
                                            bf16* __restrict__ qA,
                                            bf16* __restrict__ kA,
                                            bf16* __restrict__ vA) {
  const int z = blockIdx.y;
  const float* src = (z == 0) ? q : (z == 1) ? k : v;
  bf16* dst = (z == 0) ? qA : (z == 1) ? kA : vA;
  const size_t i = ((size_t)blockIdx.x * 256 + threadIdx.x) * 4;
  f32x4 x = *(const f32x4*)(src + i);
  bf16x4 o;
#pragma unroll
  for (int j = 0; j < 4; j++) o[j] = (bf16)x[j];
  *(bf16x4*)(dst + i) = o;
}

// ===================== weight transpose prepass =====================
// W [k][n] fp32 -> WT [n][k] bf16 (z<3: hi only; z==3: Wo -> hi and lo)
__global__ __launch_bounds__(256) void wtrans(
    const float* __restrict__ Wq, const float* __restrict__ Wk,
    const float* __restrict__ Wv, const float* __restrict__ Wo,
    bf16* __restrict__ WTq, bf16* __restrict__ WTk, bf16* __restrict__ WTv,
    bf16* __restrict__ WoTh, bf16* __restrict__ WoTl) {
  __shared__ float T[64 * 68];
  const int z = blockIdx.z;
  const float* W = (z == 0) ? Wq : (z == 1) ? Wk : (z == 2) ? Wv : Wo;
  const int n0 = blockIdx.x * 64, k0 = blockIdx.y * 64;
  const int tid = threadIdx.x;
  const int lr = tid >> 4, lc = (tid & 15) * 4;
#pragma unroll
  for (int r = 0; r < 4; r++) {
    f32x4 v = *(const f32x4*)(W + (size_t)(k0 + r * 16 + lr) * 1024 + n0 + lc);
    *(f32x4*)&T[(r * 16 + lr) * 68 + lc] = v;
  }
  __syncthreads();
  const int nn = tid >> 3, kc = (tid & 7) * 8;
#pragma unroll
  for (int p = 0; p < 2; p++) {
    int n = p * 32 + nn;
    bf16x8 h, l;
#pragma unroll
    for (int j = 0; j < 8; j++) {
      float v = T[(kc + j) * 68 + n];
      bf16 hh = (bf16)v;
      h[j] = hh;
      l[j] = (bf16)(v - (float)hh);
    }
    if (z < 3) {
      bf16* WT = (z == 0) ? WTq : (z == 1) ? WTk : WTv;
      *(bf16x8*)(WT + (size_t)(n0 + n) * 1024 + k0 + kc) = h;
    } else {
      *(bf16x8*)(WoTh + (size_t)(n0 + n) * 1024 + k0 + kc) = h;
      *(bf16x8*)(WoTl + (size_t)(n0 + n) * 1024 + k0 + kc) = l;
    }
  }
}

// ---- swizzled bf16 tile staging (rows of 32 bf16 = 64B, 4 granules) ----
// phys(r,g) = r*64B + ((g + (r>>1))&3)*16B  -> 2-way conflict max (free).
// One async16 covers a 16-row chunk: lane = rl*4 + pos; fetches g=(pos-(rl>>1))&3.

// ===================== fused QKV GEMM (bf16, swizzled async staging) ============
// z=0: Q*QSCALE -> bf16 [B,H,S,DH]; z=1: K; z=2: V^T [B*H,DH,S]
__global__ __launch_bounds__(256) void gemm_qkv(
    const bf16* __restrict__ Aq, const bf16* __restrict__ Ak,
    const bf16* __restrict__ Av, const bf16* __restrict__ WTq,
    const bf16* __restrict__ WTk, const bf16* __restrict__ WTv,
    const float* __restrict__ bq, const float* __restrict__ bk,
    const float* __restrict__ bv, bf16* __restrict__ Qb,
    bf16* __restrict__ Kb, bf16* __restrict__ VT) {
  __shared__ char smem[34816];  // staging: A [0,8K) B [8K,16K); epilogue T 34816

  const int z = blockIdx.z;
  const bf16* A = (z == 0) ? Aq : (z == 1) ? Ak : Av;
  const bf16* WT = (z == 0) ? WTq : (z == 1) ? WTk : WTv;
  const float* bias = (z == 0) ? bq : (z == 1) ? bk : bv;
  const float oscale = (z == 0) ? QSCALE : 1.0f;

  const int tid = threadIdx.x;
  const int bn = blockIdx.x * 128;
  const int bm = blockIdx.y * 128;
  const int wv = tid >> 6;
  const int lane = tid & 63;
  const int quad = lane >> 4;
  const int lo = lane & 15;
  const int wm = (wv >> 1) * 64;
  const int wn = (wv & 1) * 64;

  f32x4 acc[4][4];
#pragma unroll
  for (int i = 0; i < 4; i++)
#pragma unroll
    for (int j = 0; j < 4; j++) acc[i][j] = {0.f, 0.f, 0.f, 0.f};

  const int rl = lane >> 2;                    // staging: row in 16-chunk
  const int gS = ((lane & 3) - (rl >> 1)) & 3; // staging: granule to fetch
  const int pos = (quad + (lo >> 1)) & 3;      // frag read position

  for (int kt = 0; kt < 32; ++kt) {
#pragma unroll
    for (int j = 0; j < 2; j++) {
      int chunk = wv * 2 + j;
      async16(smem + chunk * 1024,
              A + (size_t)(bm + chunk * 16 + rl) * 1024 + kt * 32 + gS * 8);
      async16(smem + 8192 + chunk * 1024,
              WT + (size_t)(bn + chunk * 16 + rl) * 1024 + kt * 32 + gS * 8);
    }
    __syncthreads();

    bf16x8 af[4], bfr[4];
    const char* ab = smem + (wm + lo) * 64 + pos * 16;
    const char* bb = smem + 8192 + (wn + lo) * 64 + pos * 16;
#pragma unroll
    for (int mi = 0; mi < 4; mi++) af[mi] = *(const bf16x8*)(ab + mi * 1024);
#pragma unroll
    for (int ni = 0; ni < 4; ni++) bfr[ni] = *(const bf16x8*)(bb + ni * 1024);
#pragma unroll
    for (int mi = 0; mi < 4; mi++)
#pragma unroll
      for (int ni = 0; ni < 4; ni++)
        acc[mi][ni] = __builtin_amdgcn_mfma_f32_16x16x32_bf16(af[mi], bfr[ni], acc[mi][ni], 0, 0, 0);
    __syncthreads();
  }

  const int b = bm >> 11;
  const int srow0 = bm & (S - 1);

  if (z == 2) {  // V^T: direct bf16x4 stores [bh][dh][s]
#pragma unroll
    for (int mi = 0; mi < 4; mi++)
#pragma unroll
      for (int ni = 0; ni < 4; ni++) {
        int col = bn + wn + ni * 16 + lo;
        int h = col >> 6, dh = col & 63;
        float bvv = bias[col];
        bf16x4 t;
#pragma unroll
        for (int r = 0; r < 4; r++) t[r] = (bf16)(acc[mi][ni][r] + bvv);
        int s0 = srow0 + wm + mi * 16 + quad * 4;
        *(bf16x4*)&VT[(((size_t)(b * H + h)) * DH + dh) * S + s0] = t;
      }
    return;
  }

  // Q/K: LDS transpose -> coalesced [bh][s][dh] stores
  bf16* T = (bf16*)smem;  // [128][136]
#pragma unroll
  for (int mi = 0; mi < 4; mi++)
#pragma unroll
    for (int ni = 0; ni < 4; ni++) {
      int col = wn + ni * 16 + lo;
      float bvv = bias[bn + col];
#pragma unroll
      for (int r = 0; r < 4; r++) {
        int row = wm + mi * 16 + quad * 4 + r;
        T[row * 136 + col] = (bf16)((acc[mi][ni][r] + bvv) * oscale);
      }
    }
  __syncthreads();
  bf16* out = (z == 0) ? Qb : Kb;
  const int rr = tid >> 1;
  const int half = tid & 1;
  const int h = (bn >> 6) + half;
  bf16* gp = out + (((size_t)(b * H + h)) * S + srow0 + rr) * DH;
#pragma unroll
  for (int j = 0; j < 8; j++)
    *(bf16x8*)(gp + j * 8) = *(const bf16x8*)&T[rr * 136 + half * 64 + j * 8];
}

// ===================== O-projection: fused 3-term, K-split x2 =====================
// acc = Ah*Wh + Ah*Wl + Al*Wh ; z=0 (k 0..511) -> dout raw; z=1 (k 512..1023) -> P1 raw
__global__ __launch_bounds__(256) void gemm_o(
    const bf16* __restrict__ AOh, const bf16* __restrict__ AOl,
    const bf16* __restrict__ Wh, const bf16* __restrict__ Wl,
    float* __restrict__ dout, float* __restrict__ P1) {
  __shared__ char smem[32768];  // Ah | Al | Bh | Bl (8K each)

  const int z = blockIdx.z;
  float* out = (z == 0) ? dout : P1;

  const int tid = threadIdx.x;
  const int bn = blockIdx.x * 128;
  const int bm = blockIdx.y * 128;
  const int wv = tid >> 6;
  const int lane = tid & 63;
  const int quad = lane >> 4;
  const int lo = lane & 15;
  const int wm = (wv >> 1) * 64;
  const int wn = (wv & 1) * 64;

  f32x4 acc[4][4];
#pragma unroll
  for (int i = 0; i < 4; i++)
#pragma unroll
    for (int j = 0; j < 4; j++) acc[i][j] = {0.f, 0.f, 0.f, 0.f};

  const int rl = lane >> 2;
  const int gS = ((lane & 3) - (rl >> 1)) & 3;
  const int pos = (quad + (lo >> 1)) & 3;

  for (int kt = z * 16; kt < z * 16 + 16; ++kt) {
#pragma unroll
    for (int j = 0; j < 2; j++) {
      int chunk = wv * 2 + j;
      size_t arow = (size_t)(bm + chunk * 16 + rl) * 1024 + kt * 32 + gS * 8;
      size_t brow = (size_t)(bn + chunk * 16 + rl) * 1024 + kt * 32 + gS * 8;
      async16(smem + chunk * 1024, AOh + arow);
      async16(smem + 8192 + chunk * 1024, AOl + arow);
      async16(smem + 16384 + chunk * 1024, Wh + brow);
      async16(smem + 24576 + chunk * 1024, Wl + brow);
    }
    __syncthreads();

    bf16x8 ah[4], al[4], bh[4], bl[4];
    const char* ap = smem + (wm + lo) * 64 + pos * 16;
    const char* bp = smem + 16384 + (wn + lo) * 64 + pos * 16;
#pragma unroll
    for (int mi = 0; mi < 4; mi++) {
      ah[mi] = *(const bf16x8*)(ap + mi * 1024);
      al[mi] = *(const bf16x8*)(ap + 8192 + mi * 1024);
    }
#pragma unroll
    for (int ni = 0; ni < 4; ni++) {
      bh[ni] = *(const bf16x8*)(bp + ni * 1024);
      bl[ni] = *(const bf16x8*)(bp + 8192 + ni * 1024);
    }
#pragma unroll
    for (int mi = 0; mi < 4; mi++)
#pragma unroll
      for (int ni = 0; ni < 4; ni++) {
        acc[mi][ni] = __builtin_amdgcn_mfma_f32_16x16x32_bf16(ah[mi], bh[ni], acc[mi][ni], 0, 0, 0);
        acc[mi][ni] = __builtin_amdgcn_mfma_f32_16x16x32_bf16(ah[mi], bl[ni], acc[mi][ni], 0, 0, 0);
        acc[mi][ni] = __builtin_amdgcn_mfma_f32_16x16x32_bf16(al[mi], bh[ni], acc[mi][ni], 0, 0, 0);
      }
    __syncthreads();
  }

#pragma unroll
  for (int mi = 0; mi < 4; mi++)
#pragma unroll
    for (int ni = 0; ni < 4; ni++) {
      int col = bn + wn + ni * 16 + lo;
#pragma unroll
      for (int r = 0; r < 4; r++) {
        int row = bm + wm + mi * 16 + quad * 4 + r;
        out[(size_t)row * 1024 + col] = acc[mi][ni][r];
      }
    }
}

// ===================== combine: dout = dout + P1 + bias =====================
__global__ __launch_bounds__(256) void combine_o(const float* __restrict__ P1,
                                                 const float* __restrict__ bias,
                                                 float* __restrict__ out) {
  const size_t i = ((size_t)blockIdx.x * 256 + threadIdx.x) * 4;
  f32x4 a = *(const f32x4*)(out + i);
  f32x4 p = *(const f32x4*)(P1 + i);
  f32x4 bv = *(const f32x4*)(bias + ((int)i & 1023));
  f32x4 r;
#pragma unroll
  for (int j = 0; j < 4; j++) r[j] = a[j] + p[j] + bv[j];
  *(f32x4*)(out + i) = r;
}

// ===================== mask -> bitmask =====================
__global__ __launch_bounds__(256) void maskbits_kernel(
    const int* __restrict__ mask, uint64_t* __restrict__ MB) {
  const int gid = blockIdx.x * 4 + (threadIdx.x >> 6);
  const int lane = threadIdx.x & 63;
  const int kt = gid >> 11;
  const int q = gid & (S - 1);
  int v = mask[(size_t)q * S + kt * 64 + lane];
  uint64_t bits = __ballot(v != 0);
  if (lane == 0) MB[(size_t)kt * S + q] = bits;
}

// ===================== attention: 2-way key-split, double-buffered P ============
// P tile: [32 q][64 key] bf16, 128B rows, 8B-granule XOR swizzle (2-way max).
__global__ __launch_bounds__(512, 4) void attn_kernel(
    const bf16* __restrict__ Qg, const bf16* __restrict__ Kg,
    const bf16* __restrict__ VTg, const uint64_t* __restrict__ MB,
    bf16* __restrict__ AOh, bf16* __restrict__ AOl) {
  __shared__ bf16 Ps[8][2][32 * 64];  // 65536 B; also the combine buffer

  const int tid = threadIdx.x;
  const int wv = tid >> 6;
  const int lane = tid & 63;
  const int quad = lane >> 4;
  const int lo = lane & 15;
  const int ks = wv >> 2;  // key half
  const int wq = wv & 3;   // q-group

  const int lin = blockIdx.x;  // 512 blocks
  const int bh = (lin & 7) * 4 + ((lin >> 3) & 3);  // XCD-local K/V set
  const int qt = lin >> 5;                          // 0..15
  const int qbase = qt * 128 + wq * 32;
  const size_t base = (size_t)bh * S * DH;
  const int xm = (lo & 7) << 1;  // P-swizzle mask

  bf16x8 qf[2][2];
#pragma unroll
  for (int nq = 0; nq < 2; nq++) {
    const bf16* qp = Qg + base + (size_t)(qbase + nq * 16 + lo) * DH + quad * 8;
    qf[nq][0] = *(const bf16x8*)qp;
    qf[nq][1] = *(const bf16x8*)(qp + 32);
  }

  f32x4 Oacc[2][4];
#pragma unroll
  for (int i = 0; i < 2; i++)
#pragma unroll
    for (int j = 0; j < 4; j++) Oacc[i][j] = {0.f, 0.f, 0.f, 0.f};
  float lpart[2] = {0.f, 0.f};

#pragma unroll 2
  for (int kt = ks * 16; kt < ks * 16 + 16; ++kt) {
    bf16* Pw = Ps[wv][kt & 1];

    uint64_t m0 = MB[(size_t)kt * S + qbase + lo] >> (quad * 4);
    uint64_t m1 = MB[(size_t)kt * S + qbase + 16 + lo] >> (quad * 4);
    uint32_t mw[2][2] = {{(uint32_t)m0, (uint32_t)(m0 >> 32)},
                         {(uint32_t)m1, (uint32_t)(m1 >> 32)}};

    f32x4 sacc[4][2];
#pragma unroll
    for (int mi = 0; mi < 4; mi++)
#pragma unroll
      for (int nq = 0; nq < 2; nq++) sacc[mi][nq] = {0.f, 0.f, 0.f, 0.f};
#pragma unroll
    for (int mi = 0; mi < 4; mi++) {
      const bf16* kp = Kg + base + (size_t)(kt * 64 + mi * 16 + lo) * DH + quad * 8;
      bf16x8 k0 = *(const bf16x8*)kp;
      bf16x8 k1 = *(const bf16x8*)(kp + 32);
#pragma unroll
      for (int nq = 0; nq < 2; nq++) {
        sacc[mi][nq] = __builtin_amdgcn_mfma_f32_16x16x32_bf16(k0, qf[nq][0], sacc[mi][nq], 0, 0, 0);
        sacc[mi][nq] = __builtin_amdgcn_mfma_f32_16x16x32_bf16(k1, qf[nq][1], sacc[mi][nq], 0, 0, 0);
      }
    }

    // p = bit ? exp2(s) : 0 ; row-sums; pack into swizzled P
#pragma unroll
    for (int mi = 0; mi < 4; mi++)
#pragma unroll
      for (int nq = 0; nq < 2; nq++) {
        bf16x4 t;
#pragma unroll
        for (int r = 0; r < 4; r++) {
          float p = exp2f(sacc[mi][nq][r]);
          p = ((mw[nq][mi >> 1] >> (((mi & 1) << 4) + r)) & 1) ? p : 0.0f;
          lpart[nq] += p;
          t[r] = (bf16)p;
        }
        // logical 8B granule g = mi*4+quad at row nq*16+lo -> phys g^xm
        *(bf16x4*)&Pw[(nq * 16 + lo) * 64 + (((mi * 4 + quad) ^ xm) * 4)] = t;
      }

#pragma unroll
    for (int kk = 0; kk < 2; kk++) {
      int g16 = kk * 8 + quad * 2;
      bf16x8 pa0 = *(const bf16x8*)&Pw[lo * 64 + ((g16 ^ xm) * 4)];
      bf16x8 pa1 = *(const bf16x8*)&Pw[(16 + lo) * 64 + ((g16 ^ xm) * 4)];
#pragma unroll
      for (int ni = 0; ni < 4; ni++) {
        bf16x8 vb = *(const bf16x8*)(VTg + ((size_t)bh * DH + ni * 16 + lo) * S +
                                     kt * 64 + kk * 32 + quad * 8);
        Oacc[0][ni] = __builtin_amdgcn_mfma_f32_16x16x32_bf16(pa0, vb, Oacc[0][ni], 0, 0, 0);
        Oacc[1][ni] = __builtin_amdgcn_mfma_f32_16x16x32_bf16(pa1, vb, Oacc[1][ni], 0, 0, 0);
      }
    }
  }

#pragma unroll
  for (int nq = 0; nq < 2; nq++) {
    lpart[nq] += __shfl_xor(lpart[nq], 16);
    lpart[nq] += __shfl_xor(lpart[nq], 32);
  }

  // combine the two key halves through LDS
  float* CB = (float*)Ps;
  __syncthreads();
  if (ks == 1) {
    float* p = CB + (size_t)(wq * 64 + lane) * 36;
#pragma unroll
    for (int qmi = 0; qmi < 2; qmi++)
#pragma unroll
      for (int ni = 0; ni < 4; ni++) *(f32x4*)(p + (qmi * 4 + ni) * 4) = Oacc[qmi][ni];
    p[32] = lpart[0];
    p[33] = lpart[1];
  }
  __syncthreads();
  if (ks == 0) {
    float* p = CB + (size_t)(wq * 64 + lane) * 36;
#pragma unroll
    for (int qmi = 0; qmi < 2; qmi++)
#pragma unroll
      for (int ni = 0; ni < 4; ni++) {
        f32x4 o = *(const f32x4*)(p + (qmi * 4 + ni) * 4);
#pragma unroll
        for (int r = 0; r < 4; r++) Oacc[qmi][ni][r] += o[r];
      }
    lpart[0] += p[32];
    lpart[1] += p[33];

    const int b = bh >> 4, h = bh & (H - 1);
#pragma unroll
    for (int qmi = 0; qmi < 2; qmi++)
#pragma unroll
      for (int r = 0; r < 4; r++) {
        float inv = 1.0f / __shfl(lpart[qmi], quad * 4 + r);
        int q = qbase + qmi * 16 + quad * 4 + r;
        size_t rowoff = (size_t)(b * S + q) * D + h * DH;
#pragma unroll
        for (int ni = 0; ni < 4; ni++) {
          float o = Oacc[qmi][ni][r] * inv;
          bf16 hi = (bf16)o;
          AOh[rowoff + ni * 16 + lo] = hi;
          AOl[rowoff + ni * 16 + lo] = (bf16)(o - (float)hi);
        }
      }
  }
}

// ===================== launch =====================
extern "C" void kernel_launch(void* const* d_in, const int* in_sizes, int n_in,
                              void* d_out, int out_size, void* d_ws,
                              size_t ws_size, hipStream_t stream) {
  const float* q = (const float*)d_in[0];
  const float* k = (const float*)d_in[1];
  const float* v = (const float*)d_in[2];
  const int* mask = (const int*)d_in[3];
  const float* w_q = (const float*)d_in[4];
  const float* b_q = (const float*)d_in[5];
  const float* w_k = (const float*)d_in[6];
  const float* b_k = (const float*)d_in[7];
  const float* w_v = (const float*)d_in[8];
  const float* b_v = (const float*)d_in[9];
  const float* w_o = (const float*)d_in[10];
  const float* b_o = (const float*)d_in[11];

  // ws (MiB offsets):
  // [0,8) Qb | [8,16) Kb | [16,24) VT | [24,32) qA | [32,40) kA | [40,48) vA
  // [48,50) WTq | [50,52) WTk | [52,54) WTv | [54,56) WoTh | [56,58) WoTl | [58,58.5) MB
  // overlays: AOh=[24,32) AOl=[32,40) (after gemm_qkv) ; P1=[0,16) (after attn)
  char* w = (char*)d_ws;
  const size_t MiB = 1ull << 20;
  bf16* Qb = (bf16*)w;
  bf16* Kb = (bf16*)(w + 8 * MiB);
  bf16* VT = (bf16*)(w + 16 * MiB);
  bf16* qA = (bf16*)(w + 24 * MiB);
  bf16* kA = (bf16*)(w + 32 * MiB);
  bf16* vA = (bf16*)(w + 40 * MiB);
  bf16* AOh = (bf16*)(w + 24 * MiB);
  bf16* AOl = (bf16*)(w + 32 * MiB);
  float* P1 = (float*)w;
  bf16* WTq = (bf16*)(w + 48 * MiB);
  bf16* WTk = (bf16*)(w + 50 * MiB);
  bf16* WTv = (bf16*)(w + 52 * MiB);
  bf16* WoTh = (bf16*)(w + 54 * MiB);
  bf16* WoTl = (bf16*)(w + 56 * MiB);
  uint64_t* MBits = (uint64_t*)(w + 58 * MiB);

  maskbits_kernel<<<16384, 256, 0, stream>>>(mask, MBits);
  wtrans<<<dim3(16, 16, 4), 256, 0, stream>>>(w_q, w_k, w_v, w_o, WTq, WTk, WTv,
                                              WoTh, WoTl);
  cvt3<<<dim3(4096, 3), 256, 0, stream>>>(q, k, v, qA, kA, vA);
  gemm_qkv<<<dim3(8, 32, 3), 256, 0, stream>>>(qA, kA, vA, WTq, WTk, WTv, b_q,
                                               b_k, b_v, Qb, Kb, VT);
  attn_kernel<<<dim3(512), 512, 0, stream>>>(Qb, Kb, VT, MBits, AOh, AOl);
  gemm_o<<<dim3(8, 32, 2), 256, 0, stream>>>(AOh, AOl, WoTh, WoTl,
                                             (float*)d_out, P1);
  combine_o<<<4096, 256, 0, stream>>>(P1, b_o, (float*)d_out);
}

// Round 6
// 318.317 us; speedup vs baseline: 1.2011x; 1.1314x over previous
//
#include <hip/hip_runtime.h>
#include <stdint.h>

typedef __bf16 bf16;
typedef __attribute__((ext_vector_type(4))) __bf16 bf16x4;
typedef __attribute__((ext_vector_type(8))) __bf16 bf16x8;
typedef __attribute__((ext_vector_type(4))) float f32x4;

constexpr int S = 2048;
constexpr int D = 1024;
constexpr int H = 16;
constexpr int DH = 64;
constexpr int M = 4096;  // B*S

constexpr float QSCALE = 0.18033688011112042f;  // 0.125 * log2(e)

// async global->LDS, 16B/lane; LDS dst = wave-uniform base + lane*16
__device__ __forceinline__ void async16(void* lds, const void* g) {
  __builtin_amdgcn_global_load_lds(
      (const __attribute__((address_space(1))) void*)g,
      (__attribute__((address_space(3))) void*)lds, 16, 0, 0);
}

// ===================== cvt3: q,k,v fp32 -> bf16 =====================
__global__ __launch_bounds__(256) void cvt3(const float* __restrict__ q,
                                            const float* __restrict__ k,
                                            const float* __restrict__ v,
                                            bf16* __restrict__ qA,
                                            bf16* __restrict__ kA,
                                            bf16* __restrict__ vA) {
  const int z = blockIdx.y;
  const float* src = (z == 0) ? q : (z == 1) ? k : v;
  bf16* dst = (z == 0) ? qA : (z == 1) ? kA : vA;
  const size_t i = ((size_t)blockIdx.x * 256 + threadIdx.x) * 4;
  f32x4 x = *(const f32x4*)(src + i);
  bf16x4 o;
#pragma unroll
  for (int j = 0; j < 4; j++) o[j] = (bf16)x[j];
  *(bf16x4*)(dst + i) = o;
}

// ===================== weight transpose prepass =====================
// W [k][n] fp32 -> WT [n][k] bf16 (z<3: hi only; z==3: Wo -> hi and lo)
__global__ __launch_bounds__(256) void wtrans(
    const float* __restrict__ Wq, const float* __restrict__ Wk,
    const float* __restrict__ Wv, const float* __restrict__ Wo,
    bf16* __restrict__ WTq, bf16* __restrict__ WTk, bf16* __restrict__ WTv,
    bf16* __restrict__ WoTh, bf16* __restrict__ WoTl) {
  __shared__ float T[64 * 68];
  const int z = blockIdx.z;
  const float* W = (z == 0) ? Wq : (z == 1) ? Wk : (z == 2) ? Wv : Wo;
  const int n0 = blockIdx.x * 64, k0 = blockIdx.y * 64;
  const int tid = threadIdx.x;
  const int lr = tid >> 4, lc = (tid & 15) * 4;
#pragma unroll
  for (int r = 0; r < 4; r++) {
    f32x4 v = *(const f32x4*)(W + (size_t)(k0 + r * 16 + lr) * 1024 + n0 + lc);
    *(f32x4*)&T[(r * 16 + lr) * 68 + lc] = v;
  }
  __syncthreads();
  const int nn = tid >> 3, kc = (tid & 7) * 8;
#pragma unroll
  for (int p = 0; p < 2; p++) {
    int n = p * 32 + nn;
    bf16x8 h, l;
#pragma unroll
    for (int j = 0; j < 8; j++) {
      float v = T[(kc + j) * 68 + n];
      bf16 hh = (bf16)v;
      h[j] = hh;
      l[j] = (bf16)(v - (float)hh);
    }
    if (z < 3) {
      bf16* WT = (z == 0) ? WTq : (z == 1) ? WTk : WTv;
      *(bf16x8*)(WT + (size_t)(n0 + n) * 1024 + k0 + kc) = h;
    } else {
      *(bf16x8*)(WoTh + (size_t)(n0 + n) * 1024 + k0 + kc) = h;
      *(bf16x8*)(WoTl + (size_t)(n0 + n) * 1024 + k0 + kc) = l;
    }
  }
}

// ===================== fused QKV GEMM: BK=64, XOR swizzle =====================
// Tiles 128 rows x 128B; phys granule = g ^ (row&7) -> 2-way free on reads.
// z=0: Q*QSCALE -> bf16 [B,H,S,DH]; z=1: K; z=2: V^T [B*H,DH,S]
__global__ __launch_bounds__(256) void gemm_qkv(
    const bf16* __restrict__ Aq, const bf16* __restrict__ Ak,
    const bf16* __restrict__ Av, const bf16* __restrict__ WTq,
    const bf16* __restrict__ WTk, const bf16* __restrict__ WTv,
    const float* __restrict__ bq, const float* __restrict__ bk,
    const float* __restrict__ bv, bf16* __restrict__ Qb,
    bf16* __restrict__ Kb, bf16* __restrict__ VT) {
  __shared__ char smem[34816];  // A [0,16K) B [16K,32K); epilogue T 34816B

  const int z = blockIdx.z;
  const bf16* A = (z == 0) ? Aq : (z == 1) ? Ak : Av;
  const bf16* WT = (z == 0) ? WTq : (z == 1) ? WTk : WTv;
  const float* bias = (z == 0) ? bq : (z == 1) ? bk : bv;
  const float oscale = (z == 0) ? QSCALE : 1.0f;

  const int tid = threadIdx.x;
  const int bn = blockIdx.x * 128;
  const int bm = blockIdx.y * 128;
  const int wv = tid >> 6;
  const int lane = tid & 63;
  const int quad = lane >> 4;
  const int lo = lane & 15;
  const int wm = (wv >> 1) * 64;
  const int wn = (wv & 1) * 64;

  f32x4 acc[4][4];
#pragma unroll
  for (int i = 0; i < 4; i++)
#pragma unroll
    for (int j = 0; j < 4; j++) acc[i][j] = {0.f, 0.f, 0.f, 0.f};

  const int rloc = lane >> 3;              // staging: row within 8-row chunk
  const int gx = (lane & 7) ^ rloc;        // staging: global granule (xor swz)
  const int rx = (lo & 7);                 // read swizzle key

  for (int kt = 0; kt < 16; ++kt) {
#pragma unroll
    for (int j = 0; j < 4; j++) {
      int ch = wv * 4 + j;  // 0..15, 8 rows each
      async16(smem + ch * 1024,
              A + (size_t)(bm + ch * 8 + rloc) * 1024 + kt * 64 + gx * 8);
      async16(smem + 16384 + ch * 1024,
              WT + (size_t)(bn + ch * 8 + rloc) * 1024 + kt * 64 + gx * 8);
    }
    __syncthreads();

#pragma unroll
    for (int ks = 0; ks < 2; ks++) {
      bf16x8 af[4], bfr[4];
#pragma unroll
      for (int mi = 0; mi < 4; mi++)
        af[mi] = *(const bf16x8*)(smem + (wm + mi * 16 + lo) * 128 +
                                  (((ks * 4 + quad) ^ rx) * 16));
#pragma unroll
      for (int ni = 0; ni < 4; ni++)
        bfr[ni] = *(const bf16x8*)(smem + 16384 + (wn + ni * 16 + lo) * 128 +
                                   (((ks * 4 + quad) ^ rx) * 16));
#pragma unroll
      for (int mi = 0; mi < 4; mi++)
#pragma unroll
        for (int ni = 0; ni < 4; ni++)
          acc[mi][ni] = __builtin_amdgcn_mfma_f32_16x16x32_bf16(
              af[mi], bfr[ni], acc[mi][ni], 0, 0, 0);
    }
    __syncthreads();
  }

  const int b = bm >> 11;
  const int srow0 = bm & (S - 1);

  if (z == 2) {  // V^T: direct bf16x4 stores [bh][dh][s]
#pragma unroll
    for (int mi = 0; mi < 4; mi++)
#pragma unroll
      for (int ni = 0; ni < 4; ni++) {
        int col = bn + wn + ni * 16 + lo;
        int h = col >> 6, dh = col & 63;
        float bvv = bias[col];
        bf16x4 t;
#pragma unroll
        for (int r = 0; r < 4; r++) t[r] = (bf16)(acc[mi][ni][r] + bvv);
        int s0 = srow0 + wm + mi * 16 + quad * 4;
        *(bf16x4*)&VT[(((size_t)(b * H + h)) * DH + dh) * S + s0] = t;
      }
    return;
  }

  // Q/K: LDS transpose -> coalesced [bh][s][dh] stores
  bf16* T = (bf16*)smem;  // [128][136]
#pragma unroll
  for (int mi = 0; mi < 4; mi++)
#pragma unroll
    for (int ni = 0; ni < 4; ni++) {
      int col = wn + ni * 16 + lo;
      float bvv = bias[bn + col];
#pragma unroll
      for (int r = 0; r < 4; r++) {
        int row = wm + mi * 16 + quad * 4 + r;
        T[row * 136 + col] = (bf16)((acc[mi][ni][r] + bvv) * oscale);
      }
    }
  __syncthreads();
  bf16* out = (z == 0) ? Qb : Kb;
  const int rr = tid >> 1;
  const int half = tid & 1;
  const int h = (bn >> 6) + half;
  bf16* gp = out + (((size_t)(b * H + h)) * S + srow0 + rr) * DH;
#pragma unroll
  for (int j = 0; j < 8; j++)
    *(bf16x8*)(gp + j * 8) = *(const bf16x8*)&T[rr * 136 + half * 64 + j * 8];
}

// ===================== O-projection: fused 3-term, pair-interleave swizzle ======
// BK=32 tiles: rows paired into 128B lines; phys unit u = ((g^((r>>1)&3))<<1)|(r&1)
// -> 16-lane frag reads hit 8 distinct 4-bank spans (2-way, free).
__global__ __launch_bounds__(256) void gemm_o(
    const bf16* __restrict__ AOh, const bf16* __restrict__ AOl,
    const bf16* __restrict__ Wh, const bf16* __restrict__ Wl,
    float* __restrict__ dout, float* __restrict__ P1) {
  __shared__ char smem[32768];  // Ah | Al | Bh | Bl (8K each)

  const int z = blockIdx.z;
  float* out = (z == 0) ? dout : P1;

  const int tid = threadIdx.x;
  const int bn = blockIdx.x * 128;
  const int bm = blockIdx.y * 128;
  const int wv = tid >> 6;
  const int lane = tid & 63;
  const int quad = lane >> 4;
  const int lo = lane & 15;
  const int wm = (wv >> 1) * 64;
  const int wn = (wv & 1) * 64;

  f32x4 acc[4][4];
#pragma unroll
  for (int i = 0; i < 4; i++)
#pragma unroll
    for (int j = 0; j < 4; j++) acc[i][j] = {0.f, 0.f, 0.f, 0.f};

  // staging lane decomposition (chunk = 16 rows = 8 pairs = 1024B)
  const int pl = lane >> 3;                  // pair within chunk
  const int uu = lane & 7;                   // 16B unit within pair line
  const int srow = pl * 2 + (uu & 1);        // logical row in chunk
  const int sg = (uu >> 1) ^ (pl & 3);       // logical granule fetched
  // frag-read lane constants: row = X + lo -> pair key (lo>>1)&3, parity lo&1
  const int uread = (((quad ^ ((lo >> 1) & 3)) << 1) | (lo & 1)) * 16;
  const int aoff = (lo >> 1) * 128 + uread;

  for (int kt = z * 16; kt < z * 16 + 16; ++kt) {
#pragma unroll
    for (int t = 0; t < 4; t++) {
      const bf16* src = (t == 0) ? AOh : (t == 1) ? AOl : (t == 2) ? Wh : Wl;
      int rb = (t < 2) ? bm : bn;
#pragma unroll
      for (int j = 0; j < 2; j++) {
        int c = wv * 2 + j;  // chunk 0..7
        async16(smem + t * 8192 + c * 1024,
                src + (size_t)(rb + c * 16 + srow) * 1024 + kt * 32 + sg * 8);
      }
    }
    __syncthreads();

    bf16x8 ah[4], al[4], bh[4], bl[4];
    const char* ap = smem + wm * 64 + aoff;
    const char* bp = smem + 16384 + wn * 64 + aoff;
#pragma unroll
    for (int mi = 0; mi < 4; mi++) {
      ah[mi] = *(const bf16x8*)(ap + mi * 1024);
      al[mi] = *(const bf16x8*)(ap + 8192 + mi * 1024);
    }
#pragma unroll
    for (int ni = 0; ni < 4; ni++) {
      bh[ni] = *(const bf16x8*)(bp + ni * 1024);
      bl[ni] = *(const bf16x8*)(bp + 8192 + ni * 1024);
    }
#pragma unroll
    for (int mi = 0; mi < 4; mi++)
#pragma unroll
      for (int ni = 0; ni < 4; ni++) {
        acc[mi][ni] = __builtin_amdgcn_mfma_f32_16x16x32_bf16(ah[mi], bh[ni], acc[mi][ni], 0, 0, 0);
        acc[mi][ni] = __builtin_amdgcn_mfma_f32_16x16x32_bf16(ah[mi], bl[ni], acc[mi][ni], 0, 0, 0);
        acc[mi][ni] = __builtin_amdgcn_mfma_f32_16x16x32_bf16(al[mi], bh[ni], acc[mi][ni], 0, 0, 0);
      }
    __syncthreads();
  }

#pragma unroll
  for (int mi = 0; mi < 4; mi++)
#pragma unroll
    for (int ni = 0; ni < 4; ni++) {
      int col = bn + wn + ni * 16 + lo;
#pragma unroll
      for (int r = 0; r < 4; r++) {
        int row = bm + wm + mi * 16 + quad * 4 + r;
        out[(size_t)row * 1024 + col] = acc[mi][ni][r];
      }
    }
}

// ===================== combine: dout = dout + P1 + bias =====================
__global__ __launch_bounds__(256) void combine_o(const float* __restrict__ P1,
                                                 const float* __restrict__ bias,
                                                 float* __restrict__ out) {
  const size_t i = ((size_t)blockIdx.x * 256 + threadIdx.x) * 4;
  f32x4 a = *(const f32x4*)(out + i);
  f32x4 p = *(const f32x4*)(P1 + i);
  f32x4 bv = *(const f32x4*)(bias + ((int)i & 1023));
  f32x4 r;
#pragma unroll
  for (int j = 0; j < 4; j++) r[j] = a[j] + p[j] + bv[j];
  *(f32x4*)(out + i) = r;
}

// ===================== mask -> bitmask =====================
__global__ __launch_bounds__(256) void maskbits_kernel(
    const int* __restrict__ mask, uint64_t* __restrict__ MB) {
  const int gid = blockIdx.x * 4 + (threadIdx.x >> 6);
  const int lane = threadIdx.x & 63;
  const int kt = gid >> 11;
  const int q = gid & (S - 1);
  int v = mask[(size_t)q * S + kt * 64 + lane];
  uint64_t bits = __ballot(v != 0);
  if (lane == 0) MB[(size_t)kt * S + q] = bits;
}

// ===================== attention: LDS-staged K/V, 2-way key-split =====================
// LDS: Ka|Kb|Va|Vb 8KB each (64 rows x 128B, xor swizzle) at [0,32K);
// P per-wave 4KB at [32K,64K); combine buffer reuses [0,36864).
__global__ __launch_bounds__(512) void attn_kernel(
    const bf16* __restrict__ Qg, const bf16* __restrict__ Kg,
    const bf16* __restrict__ VTg, const uint64_t* __restrict__ MB,
    bf16* __restrict__ AOh, bf16* __restrict__ AOl) {
  __shared__ char smem[65536];

  const int tid = threadIdx.x;
  const int wv = tid >> 6;
  const int lane = tid & 63;
  const int quad = lane >> 4;
  const int lo = lane & 15;
  const int ks = wv >> 2;  // key half
  const int wq = wv & 3;   // q-group

  const int lin = blockIdx.x;  // 512 blocks
  const int bh = (lin & 7) * 4 + ((lin >> 3) & 3);  // XCD-local K/V set
  const int qt = lin >> 5;                          // 0..15
  const int qbase = qt * 128 + wq * 32;
  const size_t base = (size_t)bh * S * DH;
  bf16* Pw = (bf16*)(smem + 32768 + wv * 4096);  // [32][64] bf16
  const int xm = (lo & 7) << 1;                  // P-swizzle mask (8B granules)

  // staging constants
  const int w2 = wv >> 1;    // tile: 0=Ka 1=Kb 2=Va 3=Vb
  const int whalf = wv & 1;  // chunk half within tile
  const int rloc = lane >> 3;
  const int gx = (lane & 7) ^ rloc;
  const int rx = lo & 7;  // read swizzle key

  bf16x8 qf[2][2];
#pragma unroll
  for (int nq = 0; nq < 2; nq++) {
    const bf16* qp = Qg + base + (size_t)(qbase + nq * 16 + lo) * DH + quad * 8;
    qf[nq][0] = *(const bf16x8*)qp;
    qf[nq][1] = *(const bf16x8*)(qp + 32);
  }

  f32x4 Oacc[2][4];
#pragma unroll
  for (int i = 0; i < 2; i++)
#pragma unroll
    for (int j = 0; j < 4; j++) Oacc[i][j] = {0.f, 0.f, 0.f, 0.f};
  float lpart[2] = {0.f, 0.f};

  const char* Kls = smem + ks * 8192;
  const char* Vls = smem + 16384 + ks * 8192;

  for (int kt16 = 0; kt16 < 16; ++kt16) {
    // ---- stage K/V tiles for both key halves (coalesced, 4 async16/wave) ----
    {
      const int kta = kt16 + (w2 & 1) * 16;  // tiles 0,2 -> kt16 ; 1,3 -> +16
#pragma unroll
      for (int j = 0; j < 4; j++) {
        int cit = whalf * 4 + j;  // chunk in tile, 8 rows each
        char* dst = smem + w2 * 8192 + cit * 1024;
        int row = cit * 8 + rloc;
        if (w2 < 2)  // K tile: rows = key
          async16(dst, Kg + base + (size_t)(kta * 64 + row) * 64 + gx * 8);
        else  // V tile: rows = dh, cols = key
          async16(dst, VTg + base + (size_t)row * S + kta * 64 + gx * 8);
      }
    }
    const int kt = ks * 16 + kt16;

    // mask words (global; overlaps staging wait)
    uint64_t m0 = MB[(size_t)kt * S + qbase + lo] >> (quad * 4);
    uint64_t m1 = MB[(size_t)kt * S + qbase + 16 + lo] >> (quad * 4);
    uint32_t mw[2][2] = {{(uint32_t)m0, (uint32_t)(m0 >> 32)},
                         {(uint32_t)m1, (uint32_t)(m1 >> 32)}};

    __syncthreads();  // staging landed

    // ---- S^T = K Q^T from LDS K tile ----
    f32x4 sacc[4][2];
#pragma unroll
    for (int mi = 0; mi < 4; mi++)
#pragma unroll
      for (int nq = 0; nq < 2; nq++) sacc[mi][nq] = {0.f, 0.f, 0.f, 0.f};
#pragma unroll
    for (int mi = 0; mi < 4; mi++) {
      bf16x8 k0 = *(const bf16x8*)(Kls + (mi * 16 + lo) * 128 + ((quad ^ rx) * 16));
      bf16x8 k1 = *(const bf16x8*)(Kls + (mi * 16 + lo) * 128 + (((4 + quad) ^ rx) * 16));
#pragma unroll
      for (int nq = 0; nq < 2; nq++) {
        sacc[mi][nq] = __builtin_amdgcn_mfma_f32_16x16x32_bf16(k0, qf[nq][0], sacc[mi][nq], 0, 0, 0);
        sacc[mi][nq] = __builtin_amdgcn_mfma_f32_16x16x32_bf16(k1, qf[nq][1], sacc[mi][nq], 0, 0, 0);
      }
    }

    // ---- p = bit ? exp2(s) : 0 ; row-sums; pack into swizzled P ----
#pragma unroll
    for (int mi = 0; mi < 4; mi++)
#pragma unroll
      for (int nq = 0; nq < 2; nq++) {
        bf16x4 t;
#pragma unroll
        for (int r = 0; r < 4; r++) {
          float p = exp2f(sacc[mi][nq][r]);
          p = ((mw[nq][mi >> 1] >> (((mi & 1) << 4) + r)) & 1) ? p : 0.0f;
          lpart[nq] += p;
          t[r] = (bf16)p;
        }
        *(bf16x4*)&Pw[(nq * 16 + lo) * 64 + (((mi * 4 + quad) ^ xm) * 4)] = t;
      }

    // ---- O += P V from LDS V tile ----
#pragma unroll
    for (int kk = 0; kk < 2; kk++) {
      int g16 = kk * 8 + quad * 2;
      bf16x8 pa0 = *(const bf16x8*)&Pw[lo * 64 + ((g16 ^ xm) * 4)];
      bf16x8 pa1 = *(const bf16x8*)&Pw[(16 + lo) * 64 + ((g16 ^ xm) * 4)];
#pragma unroll
      for (int ni = 0; ni < 4; ni++) {
        bf16x8 vb = *(const bf16x8*)(Vls + (ni * 16 + lo) * 128 +
                                     (((kk * 4 + quad) ^ rx) * 16));
        Oacc[0][ni] = __builtin_amdgcn_mfma_f32_16x16x32_bf16(pa0, vb, Oacc[0][ni], 0, 0, 0);
        Oacc[1][ni] = __builtin_amdgcn_mfma_f32_16x16x32_bf16(pa1, vb, Oacc[1][ni], 0, 0, 0);
      }
    }
    __syncthreads();  // before restaging
  }

#pragma unroll
  for (int nq = 0; nq < 2; nq++) {
    lpart[nq] += __shfl_xor(lpart[nq], 16);
    lpart[nq] += __shfl_xor(lpart[nq], 32);
  }

  // ---- combine the two key halves through LDS (reuses [0,36864)) ----
  float* CB = (float*)smem;
  __syncthreads();
  if (ks == 1) {
    float* p = CB + (size_t)(wq * 64 + lane) * 36;
#pragma unroll
    for (int qmi = 0; qmi < 2; qmi++)
#pragma unroll
      for (int ni = 0; ni < 4; ni++) *(f32x4*)(p + (qmi * 4 + ni) * 4) = Oacc[qmi][ni];
    p[32] = lpart[0];
    p[33] = lpart[1];
  }
  __syncthreads();
  if (ks == 0) {
    float* p = CB + (size_t)(wq * 64 + lane) * 36;
#pragma unroll
    for (int qmi = 0; qmi < 2; qmi++)
#pragma unroll
      for (int ni = 0; ni < 4; ni++) {
        f32x4 o = *(const f32x4*)(p + (qmi * 4 + ni) * 4);
#pragma unroll
        for (int r = 0; r < 4; r++) Oacc[qmi][ni][r] += o[r];
      }
    lpart[0] += p[32];
    lpart[1] += p[33];

    const int b = bh >> 4, h = bh & (H - 1);
#pragma unroll
    for (int qmi = 0; qmi < 2; qmi++)
#pragma unroll
      for (int r = 0; r < 4; r++) {
        float inv = 1.0f / __shfl(lpart[qmi], quad * 4 + r);
        int q = qbase + qmi * 16 + quad * 4 + r;
        size_t rowoff = (size_t)(b * S + q) * D + h * DH;
#pragma unroll
        for (int ni = 0; ni < 4; ni++) {
          float o = Oacc[qmi][ni][r] * inv;
          bf16 hi = (bf16)o;
          AOh[rowoff + ni * 16 + lo] = hi;
          AOl[rowoff + ni * 16 + lo] = (bf16)(o - (float)hi);
        }
      }
  }
}

// ===================== launch =====================
extern "C" void kernel_launch(void* const* d_in, const int* in_sizes, int n_in,
                              void* d_out, int out_size, void* d_ws,
                              size_t ws_size, hipStream_t stream) {
  const float* q = (const float*)d_in[0];
  const float* k = (const float*)d_in[1];
  const float* v = (const float*)d_in[2];
  const int* mask = (const int*)d_in[3];
  const float* w_q = (const float*)d_in[4];
  const float* b_q = (const float*)d_in[5];
  const float* w_k = (const float*)d_in[6];
  const float* b_k = (const float*)d_in[7];
  const float* w_v = (const float*)d_in[8];
  const float* b_v = (const float*)d_in[9];
  const float* w_o = (const float*)d_in[10];
  const float* b_o = (const float*)d_in[11];

  // ws (MiB offsets):
  // [0,8) Qb | [8,16) Kb | [16,24) VT | [24,32) qA | [32,40) kA | [40,48) vA
  // [48,50) WTq | [50,52) WTk | [52,54) WTv | [54,56) WoTh | [56,58) WoTl | [58,58.5) MB
  // overlays: AOh=[24,32) AOl=[32,40) (after gemm_qkv) ; P1=[0,16) (after attn)
  char* w = (char*)d_ws;
  const size_t MiB = 1ull << 20;
  bf16* Qb = (bf16*)w;
  bf16* Kb = (bf16*)(w + 8 * MiB);
  bf16* VT = (bf16*)(w + 16 * MiB);
  bf16* qA = (bf16*)(w + 24 * MiB);
  bf16* kA = (bf16*)(w + 32 * MiB);
  bf16* vA = (bf16*)(w + 40 * MiB);
  bf16* AOh = (bf16*)(w + 24 * MiB);
  bf16* AOl = (bf16*)(w + 32 * MiB);
  float* P1 = (float*)w;
  bf16* WTq = (bf16*)(w + 48 * MiB);
  bf16* WTk = (bf16*)(w + 50 * MiB);
  bf16* WTv = (bf16*)(w + 52 * MiB);
  bf16* WoTh = (bf16*)(w + 54 * MiB);
  bf16* WoTl = (bf16*)(w + 56 * MiB);
  uint64_t* MBits = (uint64_t*)(w + 58 * MiB);

  maskbits_kernel<<<16384, 256, 0, stream>>>(mask, MBits);
  wtrans<<<dim3(16, 16, 4), 256, 0, stream>>>(w_q, w_k, w_v, w_o, WTq, WTk, WTv,
                                              WoTh, WoTl);
  cvt3<<<dim3(4096, 3), 256, 0, stream>>>(q, k, v, qA, kA, vA);
  gemm_qkv<<<dim3(8, 32, 3), 256, 0, stream>>>(qA, kA, vA, WTq, WTk, WTv, b_q,
                                               b_k, b_v, Qb, Kb, VT);
  attn_kernel<<<dim3(512), 512, 0, stream>>>(Qb, Kb, VT, MBits, AOh, AOl);
  gemm_o<<<dim3(8, 32, 2), 256, 0, stream>>>(AOh, AOl, WoTh, WoTl,
                                             (float*)d_out, P1);
  combine_o<<<4096, 256, 0, stream>>>(P1, b_o, (float*)d_out);
}

// Round 7
// 302.591 us; speedup vs baseline: 1.2635x; 1.0520x over previous
//
#include <hip/hip_runtime.h>
#include <stdint.h>

typedef __bf16 bf16;
typedef __attribute__((ext_vector_type(4))) __bf16 bf16x4;
typedef __attribute__((ext_vector_type(8))) __bf16 bf16x8;
typedef __attribute__((ext_vector_type(4))) float f32x4;

constexpr int S = 2048;
constexpr int D = 1024;
constexpr int H = 16;
constexpr int DH = 64;
constexpr int M = 4096;  // B*S

constexpr float QSCALE = 0.18033688011112042f;  // 0.125 * log2(e)

// async global->LDS, 16B/lane; LDS dst = wave-uniform base + lane*16
__device__ __forceinline__ void async16(void* lds, const void* g) {
  __builtin_amdgcn_global_load_lds(
      (const __attribute__((address_space(1))) void*)g,
      (__attribute__((address_space(3))) void*)lds, 16, 0, 0);
}

// ===================== cvt3: q,k,v fp32 -> bf16 =====================
__global__ __launch_bounds__(256) void cvt3(const float* __restrict__ q,
                                            const float* __restrict__ k,
                                            const float* __restrict__ v,
                                            bf16* __restrict__ qA,
                                            bf16* __restrict__ kA,
                                            bf16* __restrict__ vA) {
  const int z = blockIdx.y;
  const float* src = (z == 0) ? q : (z == 1) ? k : v;
  bf16* dst = (z == 0) ? qA : (z == 1) ? kA : vA;
  const size_t i = ((size_t)blockIdx.x * 256 + threadIdx.x) * 4;
  f32x4 x = *(const f32x4*)(src + i);
  bf16x4 o;
#pragma unroll
  for (int j = 0; j < 4; j++) o[j] = (bf16)x[j];
  *(bf16x4*)(dst + i) = o;
}

// ===================== weight transpose prepass =====================
// W [k][n] fp32 -> WT [n][k] bf16 (z<3: hi only; z==3: Wo -> hi and lo)
__global__ __launch_bounds__(256) void wtrans(
    const float* __restrict__ Wq, const float* __restrict__ Wk,
    const float* __restrict__ Wv, const float* __restrict__ Wo,
    bf16* __restrict__ WTq, bf16* __restrict__ WTk, bf16* __restrict__ WTv,
    bf16* __restrict__ WoTh, bf16* __restrict__ WoTl) {
  __shared__ float T[64 * 68];
  const int z = blockIdx.z;
  const float* W = (z == 0) ? Wq : (z == 1) ? Wk : (z == 2) ? Wv : Wo;
  const int n0 = blockIdx.x * 64, k0 = blockIdx.y * 64;
  const int tid = threadIdx.x;
  const int lr = tid >> 4, lc = (tid & 15) * 4;
#pragma unroll
  for (int r = 0; r < 4; r++) {
    f32x4 v = *(const f32x4*)(W + (size_t)(k0 + r * 16 + lr) * 1024 + n0 + lc);
    *(f32x4*)&T[(r * 16 + lr) * 68 + lc] = v;
  }
  __syncthreads();
  const int nn = tid >> 3, kc = (tid & 7) * 8;
#pragma unroll
  for (int p = 0; p < 2; p++) {
    int n = p * 32 + nn;
    bf16x8 h, l;
#pragma unroll
    for (int j = 0; j < 8; j++) {
      float v = T[(kc + j) * 68 + n];
      bf16 hh = (bf16)v;
      h[j] = hh;
      l[j] = (bf16)(v - (float)hh);
    }
    if (z < 3) {
      bf16* WT = (z == 0) ? WTq : (z == 1) ? WTk : WTv;
      *(bf16x8*)(WT + (size_t)(n0 + n) * 1024 + k0 + kc) = h;
    } else {
      *(bf16x8*)(WoTh + (size_t)(n0 + n) * 1024 + k0 + kc) = h;
      *(bf16x8*)(WoTl + (size_t)(n0 + n) * 1024 + k0 + kc) = l;
    }
  }
}

// ===================== fused QKV GEMM: BK=64, XOR swizzle =====================
// Tiles 128 rows x 128B; phys granule = g ^ (row&7) -> 2-way free on reads.
// z=0: Q*QSCALE -> bf16 [B,H,S,DH]; z=1: K; z=2: V^T [B*H,DH,S]
__global__ __launch_bounds__(256) void gemm_qkv(
    const bf16* __restrict__ Aq, const bf16* __restrict__ Ak,
    const bf16* __restrict__ Av, const bf16* __restrict__ WTq,
    const bf16* __restrict__ WTk, const bf16* __restrict__ WTv,
    const float* __restrict__ bq, const float* __restrict__ bk,
    const float* __restrict__ bv, bf16* __restrict__ Qb,
    bf16* __restrict__ Kb, bf16* __restrict__ VT) {
  __shared__ char smem[34816];  // A [0,16K) B [16K,32K); epilogue T 34816B

  const int z = blockIdx.z;
  const bf16* A = (z == 0) ? Aq : (z == 1) ? Ak : Av;
  const bf16* WT = (z == 0) ? WTq : (z == 1) ? WTk : WTv;
  const float* bias = (z == 0) ? bq : (z == 1) ? bk : bv;
  const float oscale = (z == 0) ? QSCALE : 1.0f;

  const int tid = threadIdx.x;
  const int bn = blockIdx.x * 128;
  const int bm = blockIdx.y * 128;
  const int wv = tid >> 6;
  const int lane = tid & 63;
  const int quad = lane >> 4;
  const int lo = lane & 15;
  const int wm = (wv >> 1) * 64;
  const int wn = (wv & 1) * 64;

  f32x4 acc[4][4];
#pragma unroll
  for (int i = 0; i < 4; i++)
#pragma unroll
    for (int j = 0; j < 4; j++) acc[i][j] = {0.f, 0.f, 0.f, 0.f};

  const int rloc = lane >> 3;              // staging: row within 8-row chunk
  const int gx = (lane & 7) ^ rloc;        // staging: global granule (xor swz)
  const int rx = (lo & 7);                 // read swizzle key

  for (int kt = 0; kt < 16; ++kt) {
#pragma unroll
    for (int j = 0; j < 4; j++) {
      int ch = wv * 4 + j;  // 0..15, 8 rows each
      async16(smem + ch * 1024,
              A + (size_t)(bm + ch * 8 + rloc) * 1024 + kt * 64 + gx * 8);
      async16(smem + 16384 + ch * 1024,
              WT + (size_t)(bn + ch * 8 + rloc) * 1024 + kt * 64 + gx * 8);
    }
    __syncthreads();

#pragma unroll
    for (int ks = 0; ks < 2; ks++) {
      bf16x8 af[4], bfr[4];
#pragma unroll
      for (int mi = 0; mi < 4; mi++)
        af[mi] = *(const bf16x8*)(smem + (wm + mi * 16 + lo) * 128 +
                                  (((ks * 4 + quad) ^ rx) * 16));
#pragma unroll
      for (int ni = 0; ni < 4; ni++)
        bfr[ni] = *(const bf16x8*)(smem + 16384 + (wn + ni * 16 + lo) * 128 +
                                   (((ks * 4 + quad) ^ rx) * 16));
#pragma unroll
      for (int mi = 0; mi < 4; mi++)
#pragma unroll
        for (int ni = 0; ni < 4; ni++)
          acc[mi][ni] = __builtin_amdgcn_mfma_f32_16x16x32_bf16(
              af[mi], bfr[ni], acc[mi][ni], 0, 0, 0);
    }
    __syncthreads();
  }

  const int b = bm >> 11;
  const int srow0 = bm & (S - 1);

  if (z == 2) {  // V^T: direct bf16x4 stores [bh][dh][s]
#pragma unroll
    for (int mi = 0; mi < 4; mi++)
#pragma unroll
      for (int ni = 0; ni < 4; ni++) {
        int col = bn + wn + ni * 16 + lo;
        int h = col >> 6, dh = col & 63;
        float bvv = bias[col];
        bf16x4 t;
#pragma unroll
        for (int r = 0; r < 4; r++) t[r] = (bf16)(acc[mi][ni][r] + bvv);
        int s0 = srow0 + wm + mi * 16 + quad * 4;
        *(bf16x4*)&VT[(((size_t)(b * H + h)) * DH + dh) * S + s0] = t;
      }
    return;
  }

  // Q/K: LDS transpose -> coalesced [bh][s][dh] stores
  bf16* T = (bf16*)smem;  // [128][136]
#pragma unroll
  for (int mi = 0; mi < 4; mi++)
#pragma unroll
    for (int ni = 0; ni < 4; ni++) {
      int col = wn + ni * 16 + lo;
      float bvv = bias[bn + col];
#pragma unroll
      for (int r = 0; r < 4; r++) {
        int row = wm + mi * 16 + quad * 4 + r;
        T[row * 136 + col] = (bf16)((acc[mi][ni][r] + bvv) * oscale);
      }
    }
  __syncthreads();
  bf16* out = (z == 0) ? Qb : Kb;
  const int rr = tid >> 1;
  const int half = tid & 1;
  const int h = (bn >> 6) + half;
  bf16* gp = out + (((size_t)(b * H + h)) * S + srow0 + rr) * DH;
#pragma unroll
  for (int j = 0; j < 8; j++)
    *(bf16x8*)(gp + j * 8) = *(const bf16x8*)&T[rr * 136 + half * 64 + j * 8];
}

// ===================== O-projection: fused 3-term, pair-interleave swizzle ======
// BK=32 tiles: rows paired into 128B lines; phys unit u = ((g^((r>>1)&3))<<1)|(r&1)
// -> 16-lane frag reads hit 8 distinct 4-bank spans (2-way, free).
__global__ __launch_bounds__(256) void gemm_o(
    const bf16* __restrict__ AOh, const bf16* __restrict__ AOl,
    const bf16* __restrict__ Wh, const bf16* __restrict__ Wl,
    float* __restrict__ dout, float* __restrict__ P1) {
  __shared__ char smem[32768];  // Ah | Al | Bh | Bl (8K each)

  const int z = blockIdx.z;
  float* out = (z == 0) ? dout : P1;

  const int tid = threadIdx.x;
  const int bn = blockIdx.x * 128;
  const int bm = blockIdx.y * 128;
  const int wv = tid >> 6;
  const int lane = tid & 63;
  const int quad = lane >> 4;
  const int lo = lane & 15;
  const int wm = (wv >> 1) * 64;
  const int wn = (wv & 1) * 64;

  f32x4 acc[4][4];
#pragma unroll
  for (int i = 0; i < 4; i++)
#pragma unroll
    for (int j = 0; j < 4; j++) acc[i][j] = {0.f, 0.f, 0.f, 0.f};

  // staging lane decomposition (chunk = 16 rows = 8 pairs = 1024B)
  const int pl = lane >> 3;                  // pair within chunk
  const int uu = lane & 7;                   // 16B unit within pair line
  const int srow = pl * 2 + (uu & 1);        // logical row in chunk
  const int sg = (uu >> 1) ^ (pl & 3);       // logical granule fetched
  // frag-read lane constants: row = X + lo -> pair key (lo>>1)&3, parity lo&1
  const int uread = (((quad ^ ((lo >> 1) & 3)) << 1) | (lo & 1)) * 16;
  const int aoff = (lo >> 1) * 128 + uread;

  for (int kt = z * 16; kt < z * 16 + 16; ++kt) {
#pragma unroll
    for (int t = 0; t < 4; t++) {
      const bf16* src = (t == 0) ? AOh : (t == 1) ? AOl : (t == 2) ? Wh : Wl;
      int rb = (t < 2) ? bm : bn;
#pragma unroll
      for (int j = 0; j < 2; j++) {
        int c = wv * 2 + j;  // chunk 0..7
        async16(smem + t * 8192 + c * 1024,
                src + (size_t)(rb + c * 16 + srow) * 1024 + kt * 32 + sg * 8);
      }
    }
    __syncthreads();

    bf16x8 ah[4], al[4], bh[4], bl[4];
    const char* ap = smem + wm * 64 + aoff;
    const char* bp = smem + 16384 + wn * 64 + aoff;
#pragma unroll
    for (int mi = 0; mi < 4; mi++) {
      ah[mi] = *(const bf16x8*)(ap + mi * 1024);
      al[mi] = *(const bf16x8*)(ap + 8192 + mi * 1024);
    }
#pragma unroll
    for (int ni = 0; ni < 4; ni++) {
      bh[ni] = *(const bf16x8*)(bp + ni * 1024);
      bl[ni] = *(const bf16x8*)(bp + 8192 + ni * 1024);
    }
#pragma unroll
    for (int mi = 0; mi < 4; mi++)
#pragma unroll
      for (int ni = 0; ni < 4; ni++) {
        acc[mi][ni] = __builtin_amdgcn_mfma_f32_16x16x32_bf16(ah[mi], bh[ni], acc[mi][ni], 0, 0, 0);
        acc[mi][ni] = __builtin_amdgcn_mfma_f32_16x16x32_bf16(ah[mi], bl[ni], acc[mi][ni], 0, 0, 0);
        acc[mi][ni] = __builtin_amdgcn_mfma_f32_16x16x32_bf16(al[mi], bh[ni], acc[mi][ni], 0, 0, 0);
      }
    __syncthreads();
  }

#pragma unroll
  for (int mi = 0; mi < 4; mi++)
#pragma unroll
    for (int ni = 0; ni < 4; ni++) {
      int col = bn + wn + ni * 16 + lo;
#pragma unroll
      for (int r = 0; r < 4; r++) {
        int row = bm + wm + mi * 16 + quad * 4 + r;
        out[(size_t)row * 1024 + col] = acc[mi][ni][r];
      }
    }
}

// ===================== combine: dout = dout + P1 + bias =====================
__global__ __launch_bounds__(256) void combine_o(const float* __restrict__ P1,
                                                 const float* __restrict__ bias,
                                                 float* __restrict__ out) {
  const size_t i = ((size_t)blockIdx.x * 256 + threadIdx.x) * 4;
  f32x4 a = *(const f32x4*)(out + i);
  f32x4 p = *(const f32x4*)(P1 + i);
  f32x4 bv = *(const f32x4*)(bias + ((int)i & 1023));
  f32x4 r;
#pragma unroll
  for (int j = 0; j < 4; j++) r[j] = a[j] + p[j] + bv[j];
  *(f32x4*)(out + i) = r;
}

// ===================== mask -> bitmask =====================
__global__ __launch_bounds__(256) void maskbits_kernel(
    const int* __restrict__ mask, uint64_t* __restrict__ MB) {
  const int gid = blockIdx.x * 4 + (threadIdx.x >> 6);
  const int lane = threadIdx.x & 63;
  const int kt = gid >> 11;
  const int q = gid & (S - 1);
  int v = mask[(size_t)q * S + kt * 64 + lane];
  uint64_t bits = __ballot(v != 0);
  if (lane == 0) MB[(size_t)kt * S + q] = bits;
}

// ===================== attention: no key-split, dbuf K/V, 1 barrier/kt ============
// 8 waves x 16 q-rows. LDS: K/V dbuf 2x16KB [0,32K) + per-wave P 8x2KB [32K,48K).
__global__ __launch_bounds__(512) void attn_kernel(
    const bf16* __restrict__ Qg, const bf16* __restrict__ Kg,
    const bf16* __restrict__ VTg, const uint64_t* __restrict__ MB,
    bf16* __restrict__ AOh, bf16* __restrict__ AOl) {
  __shared__ char smem[49152];

  const int tid = threadIdx.x;
  const int wv = tid >> 6;  // 0..7
  const int lane = tid & 63;
  const int quad = lane >> 4;
  const int lo = lane & 15;

  const int lin = blockIdx.x;  // 512 blocks
  const int bh = (lin & 7) * 4 + ((lin >> 3) & 3);  // XCD-local K/V set
  const int qt = lin >> 5;                          // 0..15
  const int qbase = qt * 128 + wv * 16;
  const size_t base = (size_t)bh * S * DH;
  bf16* Pw = (bf16*)(smem + 32768 + wv * 2048);  // [16][64] bf16
  const int xm = (lo & 7) << 1;                  // P-swizzle (8B granules)

  // staging constants: 16 chunks of 1KB (8 K + 8 V), 2 per wave
  const int c0 = wv * 2;
  const int rloc = lane >> 3;
  const int gx = (lane & 7) ^ rloc;
  const int rx = lo & 7;  // read swizzle key

  // Q B-frags: 16 q-rows for this wave
  bf16x8 qf[2];
  {
    const bf16* qp = Qg + base + (size_t)(qbase + lo) * DH + quad * 8;
    qf[0] = *(const bf16x8*)qp;
    qf[1] = *(const bf16x8*)(qp + 32);
  }

  f32x4 Oacc[4];
#pragma unroll
  for (int j = 0; j < 4; j++) Oacc[j] = {0.f, 0.f, 0.f, 0.f};
  float lpart = 0.f;

#define STAGE(kt_, buf_)                                                       \
  {                                                                            \
    _Pragma("unroll") for (int j = 0; j < 2; j++) {                            \
      int c = c0 + j;                                                          \
      if (c < 8) {                                                             \
        async16((buf_) + c * 1024,                                             \
                Kg + base + (size_t)((kt_)*64 + c * 8 + rloc) * 64 + gx * 8);  \
      } else {                                                                 \
        int cv = c - 8;                                                        \
        async16((buf_) + 8192 + cv * 1024,                                     \
                VTg + base + (size_t)(cv * 8 + rloc) * S + (kt_)*64 + gx * 8); \
      }                                                                        \
    }                                                                          \
  }

  STAGE(0, smem);

  for (int kt = 0; kt < 32; ++kt) {
    const char* cur = smem + (kt & 1) * 16384;

    uint64_t m0 = MB[(size_t)kt * S + qbase + lo] >> (quad * 4);
    uint32_t mw[2] = {(uint32_t)m0, (uint32_t)(m0 >> 32)};

    __syncthreads();  // publishes stage(kt); drains loads issued last iter
    if (kt + 1 < 32) STAGE(kt + 1, smem + ((kt + 1) & 1) * 16384);

    const char* Kls = cur;
    const char* Vls = cur + 8192;

    // S^T = K Q^T
    f32x4 sacc[4];
#pragma unroll
    for (int mi = 0; mi < 4; mi++) sacc[mi] = {0.f, 0.f, 0.f, 0.f};
#pragma unroll
    for (int mi = 0; mi < 4; mi++) {
      bf16x8 k0 = *(const bf16x8*)(Kls + (mi * 16 + lo) * 128 + ((quad ^ rx) * 16));
      bf16x8 k1 = *(const bf16x8*)(Kls + (mi * 16 + lo) * 128 + (((4 + quad) ^ rx) * 16));
      sacc[mi] = __builtin_amdgcn_mfma_f32_16x16x32_bf16(k0, qf[0], sacc[mi], 0, 0, 0);
      sacc[mi] = __builtin_amdgcn_mfma_f32_16x16x32_bf16(k1, qf[1], sacc[mi], 0, 0, 0);
    }

    // p = bit ? exp2(s) : 0 ; row-sum; pack into swizzled per-wave P
#pragma unroll
    for (int mi = 0; mi < 4; mi++) {
      bf16x4 t;
#pragma unroll
      for (int r = 0; r < 4; r++) {
        float p = exp2f(sacc[mi][r]);
        p = ((mw[mi >> 1] >> (((mi & 1) << 4) + r)) & 1) ? p : 0.0f;
        lpart += p;
        t[r] = (bf16)p;
      }
      *(bf16x4*)&Pw[lo * 64 + (((mi * 4 + quad) ^ xm) * 4)] = t;
    }

    // O += P V
#pragma unroll
    for (int kk = 0; kk < 2; kk++) {
      int g16 = kk * 8 + quad * 2;
      bf16x8 pa = *(const bf16x8*)&Pw[lo * 64 + ((g16 ^ xm) * 4)];
#pragma unroll
      for (int ni = 0; ni < 4; ni++) {
        bf16x8 vb = *(const bf16x8*)(Vls + (ni * 16 + lo) * 128 +
                                     (((kk * 4 + quad) ^ rx) * 16));
        Oacc[ni] = __builtin_amdgcn_mfma_f32_16x16x32_bf16(pa, vb, Oacc[ni], 0, 0, 0);
      }
    }
  }
#undef STAGE

  // finish row-sums across quads (keys split 4/quad per mi)
  lpart += __shfl_xor(lpart, 16);
  lpart += __shfl_xor(lpart, 32);

  const int b = bh >> 4, h = bh & (H - 1);
#pragma unroll
  for (int r = 0; r < 4; r++) {
    float inv = 1.0f / __shfl(lpart, quad * 4 + r);
    int q = qbase + quad * 4 + r;
    size_t rowoff = (size_t)(b * S + q) * D + h * DH;
#pragma unroll
    for (int ni = 0; ni < 4; ni++) {
      float o = Oacc[ni][r] * inv;
      bf16 hi = (bf16)o;
      AOh[rowoff + ni * 16 + lo] = hi;
      AOl[rowoff + ni * 16 + lo] = (bf16)(o - (float)hi);
    }
  }
}

// ===================== launch =====================
extern "C" void kernel_launch(void* const* d_in, const int* in_sizes, int n_in,
                              void* d_out, int out_size, void* d_ws,
                              size_t ws_size, hipStream_t stream) {
  const float* q = (const float*)d_in[0];
  const float* k = (const float*)d_in[1];
  const float* v = (const float*)d_in[2];
  const int* mask = (const int*)d_in[3];
  const float* w_q = (const float*)d_in[4];
  const float* b_q = (const float*)d_in[5];
  const float* w_k = (const float*)d_in[6];
  const float* b_k = (const float*)d_in[7];
  const float* w_v = (const float*)d_in[8];
  const float* b_v = (const float*)d_in[9];
  const float* w_o = (const float*)d_in[10];
  const float* b_o = (const float*)d_in[11];

  // ws (MiB offsets):
  // [0,8) Qb | [8,16) Kb | [16,24) VT | [24,32) qA | [32,40) kA | [40,48) vA
  // [48,50) WTq | [50,52) WTk | [52,54) WTv | [54,56) WoTh | [56,58) WoTl | [58,58.5) MB
  // overlays: AOh=[24,32) AOl=[32,40) (after gemm_qkv) ; P1=[0,16) (after attn)
  char* w = (char*)d_ws;
  const size_t MiB = 1ull << 20;
  bf16* Qb = (bf16*)w;
  bf16* Kb = (bf16*)(w + 8 * MiB);
  bf16* VT = (bf16*)(w + 16 * MiB);
  bf16* qA = (bf16*)(w + 24 * MiB);
  bf16* kA = (bf16*)(w + 32 * MiB);
  bf16* vA = (bf16*)(w + 40 * MiB);
  bf16* AOh = (bf16*)(w + 24 * MiB);
  bf16* AOl = (bf16*)(w + 32 * MiB);
  float* P1 = (float*)w;
  bf16* WTq = (bf16*)(w + 48 * MiB);
  bf16* WTk = (bf16*)(w + 50 * MiB);
  bf16* WTv = (bf16*)(w + 52 * MiB);
  bf16* WoTh = (bf16*)(w + 54 * MiB);
  bf16* WoTl = (bf16*)(w + 56 * MiB);
  uint64_t* MBits = (uint64_t*)(w + 58 * MiB);

  maskbits_kernel<<<16384, 256, 0, stream>>>(mask, MBits);
  wtrans<<<dim3(16, 16, 4), 256, 0, stream>>>(w_q, w_k, w_v, w_o, WTq, WTk, WTv,
                                              WoTh, WoTl);
  cvt3<<<dim3(4096, 3), 256, 0, stream>>>(q, k, v, qA, kA, vA);
  gemm_qkv<<<dim3(8, 32, 3), 256, 0, stream>>>(qA, kA, vA, WTq, WTk, WTv, b_q,
                                               b_k, b_v, Qb, Kb, VT);
  attn_kernel<<<dim3(512), 512, 0, stream>>>(Qb, Kb, VT, MBits, AOh, AOl);
  gemm_o<<<dim3(8, 32, 2), 256, 0, stream>>>(AOh, AOl, WoTh, WoTl,
                                             (float*)d_out, P1);
  combine_o<<<4096, 256, 0, stream>>>(P1, b_o, (float*)d_out);
}